// Round 9
// baseline (372.863 us; speedup 1.0000x reference)
//
#include <hip/hip_runtime.h>
#include <math.h>

// ---------------------------------------------------------------------------
// TemporalGCN: 2-layer LSTM (per-node sequences) -> 2 GCN rounds -> edge MLP.
//
// R8 post-mortem: total 270us; lstm ~35-40us each (below fill noise floor).
// Root cause stands: Whh (64KB) > L1 (32KB) and the compiler refuses register
// residency (VGPR 48 across R2/R6/R7/R8) -> per-step L2-latency weight loads
// serialized into the barrier chain. R9: weights live in LDS.
//  * Unified k_lstm: S=4 seqs/block (400 blocks, 1 round @ 2 blocks/CU),
//    thread j = gate row. WhhT rows 0..57 in LDS [k][j] (lane-contiguous,
//    conflict-free), rows 58..63 in 6 regs (fits 64KB static: 64,512B).
//    q-outer weight hoist: each weight read ONCE per step, reused 4 seqs.
//    No global loads/stores inside the t-loop.
//  * k_xproj0: layer-0 input projection (K=6) precomputed into G0 with bias
//    folded, so both layers consume identical G rows.
// Dot-product accumulation order preserved exactly (absmax ~0 maintained;
// only the bias+x-dot association moved into G0 = ulp-level).
// ---------------------------------------------------------------------------

#define Hd   64
#define Ed   5
#define Fd   6
#define Bd   8
#define Wd   12
#define Nd   200
#define NSEQ (Bd*Nd)        // 1600 sequences (b,n)
#define NG   (4*Hd)         // 256 gate rows
#define NEDGE (Bd*Nd*Nd)    // 320000 edges
#define SEQB 4              // sequences per LSTM block
#define WROWS 58            // Whh k-rows staged in LDS (58*256*4 = 59,392 B)
#define LNEPS 1e-5f

__device__ __forceinline__ float sigm(float x) { return 1.0f / (1.0f + __expf(-x)); }
__device__ __forceinline__ float tanh_fast(float x) {
  float ax = fabsf(x);
  float t  = __expf(-2.0f * ax);
  float r  = (1.0f - t) / (1.0f + t);
  return copysignf(r, x);
}

// --------------------------------------------------------------------------
// Prep (flat-index dispatch):
//  [0,16384)        Wt1[k][j]    = Wih1[j][k]
//  [16384,24576)    gcnWT[r][k][u]
//  [24576,25216)    epWT[r][e][u]
//  [25216,29312)    W1aT[k][n]
//  [29312,33408)    W1bT[k][n]
//  [33408,34944)    Wt0[f][j]    = Wih0[j][f]
//  [34944,35200)    b0s[j]       = bih0[j]+bhh0[j]
//  [35200,51584)    WhhT0[k][j]  = Whh0[j][k]
//  [51584,67968)    WhhT1[k][j]  = Whh1[j][k]
__global__ __launch_bounds__(256) void k_prep(
    const float* __restrict__ Wih1, const float* __restrict__ gcn_W,
    const float* __restrict__ ep_W, const float* __restrict__ W1,
    const float* __restrict__ Wih0, const float* __restrict__ bih0,
    const float* __restrict__ bhh0, const float* __restrict__ Whh0,
    const float* __restrict__ Whh1,
    float* __restrict__ Wt1, float* __restrict__ gcnWT,
    float* __restrict__ epWT, float* __restrict__ W1aT,
    float* __restrict__ W1bT, float* __restrict__ Wt0,
    float* __restrict__ b0s, float* __restrict__ WhhT0,
    float* __restrict__ WhhT1)
{
  int idx = blockIdx.x * 256 + threadIdx.x;
  if (idx < 16384) {
    int k = idx >> 8, j = idx & 255;
    Wt1[idx] = Wih1[j * Hd + k];
  } else if (idx < 24576) {
    int r0 = idx - 16384;
    int round = r0 >> 12, rem = r0 & 4095;
    int k = rem >> 6, u = rem & 63;
    gcnWT[r0] = gcn_W[round * 4096 + u * 64 + k];
  } else if (idx < 25216) {
    int r0 = idx - 24576;
    int round = r0 / 320, rem = r0 % 320;
    int e = rem >> 6, u = rem & 63;
    epWT[r0] = ep_W[round * 320 + u * Ed + e];
  } else if (idx < 29312) {
    int r0 = idx - 25216;
    int k = r0 >> 6, n = r0 & 63;
    W1aT[r0] = W1[n * 133 + k];
  } else if (idx < 33408) {
    int r0 = idx - 29312;
    int k = r0 >> 6, n = r0 & 63;
    W1bT[r0] = W1[n * 133 + 64 + k];
  } else if (idx < 34944) {
    int r0 = idx - 33408;
    int f = r0 >> 8, j = r0 & 255;
    Wt0[r0] = Wih0[j * Fd + f];
  } else if (idx < 35200) {
    int j = idx - 34944;
    b0s[j] = bih0[j] + bhh0[j];
  } else if (idx < 51584) {
    int r0 = idx - 35200;
    int k = r0 >> 8, j = r0 & 255;
    WhhT0[r0] = Whh0[j * Hd + k];
  } else if (idx < 67968) {
    int r0 = idx - 51584;
    int k = r0 >> 8, j = r0 & 255;
    WhhT1[r0] = Whh1[j * Hd + k];
  }
}

// --------------------------------------------------------------------------
// G0 = nf-projection with bias folded: G0[row][j] = b0s[j] + sum_f x[f]*Wt0[f][j]
// row = seq*12+t. 2400 blocks x 256 thr, 8 rows/block, coalesced G0 writes.
__global__ __launch_bounds__(256) void k_xproj0(
    const float* __restrict__ nf, const float* __restrict__ Wt0,
    const float* __restrict__ b0s, float* __restrict__ G0)
{
  const int j = threadIdx.x;
  const int row0 = blockIdx.x * 8;
  float wcol[Fd];
  #pragma unroll
  for (int f = 0; f < Fd; ++f) wcol[f] = Wt0[f * NG + j];
  const float bj = b0s[j];
  #pragma unroll
  for (int r = 0; r < 8; ++r) {
    int row = row0 + r;
    int seq = row / Wd, t = row % Wd;
    int b = seq / Nd, n = seq % Nd;
    const float* xp = nf + ((b * Wd + t) * Nd + n) * Fd;
    float acc = bj;
    #pragma unroll
    for (int f = 0; f < Fd; ++f) acc += xp[f] * wcol[f];
    G0[row * NG + j] = acc;
  }
}

// --------------------------------------------------------------------------
// Unified LSTM recurrence. 400 blocks x 256 threads; block owns SEQB=4 seqs.
// Thread j = gate row j. Weights from LDS (rows 0..57) + 6 regs (58..63).
// Phase A: q-outer weight hoist, 4-seq reuse, 16 accumulators. Phase B:
// thread (su=tid>>6, uu=tid&63) owns one (seq,unit) c/h state. Two barriers
// per step; zero global memory ops inside the t-loop.
__global__ __launch_bounds__(256, 2) void k_lstm(
    const float* __restrict__ G,      // (NSEQ*Wd, NG), bias folded
    const float* __restrict__ WhhT,   // (64, 256) transposed
    float* __restrict__ yfull,        // (NSEQ, Wd, Hd)  [store_all=1]
    float* __restrict__ hlast,        // (NSEQ, Hd)      [store_all=0]
    int store_all)
{
  __shared__ float w_lds[WROWS * NG];   // 59,392 B, [k][j] lane-contiguous
  __shared__ float h_sh[SEQB][Hd];      // 1,024 B
  __shared__ float gate_sh[SEQB][NG];   // 4,096 B   (total 64,512 B)

  const int tid  = threadIdx.x;
  const int seq0 = blockIdx.x * SEQB;
  const int j    = tid;
  const int su   = tid >> 6;
  const int uu   = tid & 63;

  for (int idx = tid; idx < WROWS * NG; idx += 256) w_lds[idx] = WhhT[idx];
  float wtail[Hd - WROWS];
  #pragma unroll
  for (int q = 0; q < Hd - WROWS; ++q) wtail[q] = WhhT[(WROWS + q) * NG + j];
  h_sh[su][uu] = 0.f;

  const int jt = j >> 6;                 // 0=i,1=f,2=g,3=o (wave-uniform)
  float c = 0.f;                         // cell state for (su,uu)
  float yreg[Wd];
  float hl = 0.f;

  float gc[SEQB];
  #pragma unroll
  for (int s = 0; s < SEQB; ++s) gc[s] = G[((seq0 + s) * Wd + 0) * NG + j];
  __syncthreads();

#define WK(k) ((k) < WROWS ? w_lds[(k) * NG + j] : wtail[(k) - WROWS])

  for (int t = 0; t < Wd; ++t) {
    float gn[SEQB];
    #pragma unroll
    for (int s = 0; s < SEQB; ++s)
      gn[s] = (t + 1 < Wd) ? G[((seq0 + s) * Wd + t + 1) * NG + j] : 0.f;

    // Phase A: 16 accumulators a[s][0..3]; weights read once, reused 4x.
    float a[SEQB][4];
    #pragma unroll
    for (int s = 0; s < SEQB; ++s) {
      a[s][0] = gc[s]; a[s][1] = 0.f; a[s][2] = 0.f; a[s][3] = 0.f;
    }
    #pragma unroll
    for (int q = 0; q < 16; ++q) {
      float w0 = WK(4 * q), w1 = WK(4 * q + 1);
      float w2 = WK(4 * q + 2), w3 = WK(4 * q + 3);
      #pragma unroll
      for (int s = 0; s < SEQB; ++s) {
        float4 hv = ((const float4*)h_sh[s])[q];      // broadcast read
        a[s][q & 3] += hv.x * w0 + hv.y * w1 + hv.z * w2 + hv.w * w3;
      }
    }
    #pragma unroll
    for (int s = 0; s < SEQB; ++s) {
      float acc = (a[s][0] + a[s][1]) + (a[s][2] + a[s][3]);
      gate_sh[s][j] = (jt == 2) ? tanh_fast(acc) : sigm(acc);
    }
    __syncthreads();
    // Phase B: one (su,uu) pair per thread (4*64 = 256 exact).
    {
      float iv = gate_sh[su][uu];
      float fv = gate_sh[su][64 + uu];
      float gv = gate_sh[su][128 + uu];
      float ov = gate_sh[su][192 + uu];
      c = fv * c + iv * gv;
      float h = ov * tanh_fast(c);
      h_sh[su][uu] = h;
      yreg[t] = h;
      hl = h;
    }
    __syncthreads();
    #pragma unroll
    for (int s = 0; s < SEQB; ++s) gc[s] = gn[s];
  }
#undef WK

  if (store_all) {
    #pragma unroll
    for (int t = 0; t < Wd; ++t)
      yfull[(seq0 + su) * (Wd * Hd) + t * Hd + uu] = yreg[t];
  } else {
    hlast[(seq0 + su) * Hd + uu] = hl;
  }
}

// --------------------------------------------------------------------------
// G1 = y0 @ Wih1.T + (bih1+bhh1): (19200 x 64) @ (64 x 256).
// 300 blocks x 256 thr; lane = row, wave = 64-col slab (wave-uniform cols ->
// weights via SCALAR loads; VALU-bound). Output transposed through a 2-tile
// osh in two passes (LDS total 49.9 KB < 64 KB static limit).
__global__ __launch_bounds__(256) void k_xproj1(
    const float* __restrict__ y0,    // rows = seq*12+t
    const float* __restrict__ Wt1,   // (64,256) transposed Wih1
    const float* __restrict__ bih1, const float* __restrict__ bhh1,
    float* __restrict__ G1)          // (19200, 256)
{
  __shared__ float ysh[64 * 65];        // [r][k] pad-65: conflict-free
  __shared__ float osh[2 * 64 * 65];    // two 64x64 out tiles, pad-65

  const int tid  = threadIdx.x;
  const int row0 = blockIdx.x * 64;
  for (int idx = tid; idx < 64 * 64; idx += 256) {
    int r = idx >> 6, k = idx & 63;
    ysh[r * 65 + k] = y0[(row0 + r) * Hd + k];
  }
  __syncthreads();

  const int w = __builtin_amdgcn_readfirstlane(tid >> 6);  // force uniform
  const int r = tid & 63;
  float acc[64];
  #pragma unroll
  for (int c = 0; c < 64; ++c) acc[c] = 0.f;

  const float* wbase = Wt1 + (w << 6);
  #pragma unroll 2
  for (int k = 0; k < 64; ++k) {
    float yv = ysh[r * 65 + k];
    const float* wk = wbase + k * NG;    // uniform address -> s_load
    #pragma unroll
    for (int c = 0; c < 64; ++c) acc[c] = fmaf(yv, wk[c], acc[c]);
  }
  #pragma unroll
  for (int c = 0; c < 64; ++c) acc[c] += bih1[(w << 6) + c] + bhh1[(w << 6) + c];

  // Two passes: waves {0,1} then {2,3} dump 64x64 tiles; everyone stores.
  #pragma unroll
  for (int p = 0; p < 2; ++p) {
    __syncthreads();
    if ((w >> 1) == p) {
      float* orow = osh + ((w & 1) * 64 + r) * 65;
      #pragma unroll
      for (int c = 0; c < 64; ++c) orow[c] = acc[c];  // stride-65: no conflict
    }
    __syncthreads();
    for (int idx = tid; idx < 2 * 64 * 64; idx += 256) {
      int c  = idx & 127;              // col within this 128-col slab
      int rr = idx >> 7;               // row 0..63
      G1[(row0 + rr) * NG + p * 128 + c] =
          osh[((c >> 6) * 64 + rr) * 65 + (c & 63)];   // lanes stride-1: free
    }
  }
}

// --------------------------------------------------------------------------
// Fused per-row node pipeline: wsum -> GCN r0 -> GCN r1 -> u/v precompute.
// One block per row (b,i); 256 threads. adj/ef rows staged into LDS with
// COALESCED loads; all weight reads coalesced via the k_prep transposes.
__global__ __launch_bounds__(256) void k_node(
    const float* __restrict__ ef,    const float* __restrict__ adj,
    const float* __restrict__ h0,
    const float* __restrict__ gcnWT, const float* __restrict__ gcn_b,
    const float* __restrict__ epWT,  const float* __restrict__ ep_b,
    const float* __restrict__ ln_g,  const float* __restrict__ ln_b,
    const float* __restrict__ W1aT,  const float* __restrict__ W1bT,
    const float* __restrict__ b1,
    float* __restrict__ uu, float* __restrict__ vt)
{
  __shared__ float ef_sh[Nd * Ed];   // 1000: edge_last row (coalesced stage)
  __shared__ float adj_sh[Nd];       // 200
  __shared__ float red[4][6];
  __shared__ float w6[6];
  __shared__ float hcur[Hd];

  const int row = blockIdx.x;      // b*200+i
  const int b = row / Nd, i = row % Nd;
  const int tid = threadIdx.x;

  const float* efrow = ef + (size_t)(((b * Wd + (Wd - 1)) * Nd + i)) * (Nd * Ed);
  for (int idx = tid; idx < Nd * Ed; idx += 256) ef_sh[idx] = efrow[idx];
  const float* adjrow = adj + (b * Nd + i) * Nd;
  if (tid < Nd) adj_sh[tid] = adjrow[tid];
  if (tid < Hd) hcur[tid] = h0[row * Hd + tid];
  __syncthreads();

  // ---- wsum: p[e] = sum_j adj*edge[e], p[5] = sum_j adj (order as before)
  float p[6] = {0.f, 0.f, 0.f, 0.f, 0.f, 0.f};
  if (tid < Nd) {
    float a = adj_sh[tid];
    p[5] = a;
    #pragma unroll
    for (int k = 0; k < Ed; ++k) p[k] = a * ef_sh[tid * Ed + k];
  }
  #pragma unroll
  for (int k = 0; k < 6; ++k) {
    float v = p[k];
    for (int off = 32; off > 0; off >>= 1) v += __shfl_down(v, off);
    p[k] = v;
  }
  if ((tid & 63) == 0) {
    #pragma unroll
    for (int k = 0; k < 6; ++k) red[tid >> 6][k] = p[k];
  }
  __syncthreads();
  if (tid < 6)
    w6[tid] = red[0][tid] + red[1][tid] + red[2][tid] + red[3][tid];
  __syncthreads();

  // ---- 2 GCN rounds (wave 0; coalesced transposed-weight reads)
  const int u = tid & 63;
  #pragma unroll
  for (int round = 0; round < 2; ++round) {
    float hnew = 0.f;
    if (tid < 64) {
      const float* gwT = gcnWT + round * 4096;   // [k][u]
      const float* ewT = epWT  + round * 320;    // [e][u]
      float acc = gcn_b[round * Hd + u] + w6[5] * ep_b[round * Hd + u];
      #pragma unroll
      for (int e = 0; e < Ed; ++e) acc += w6[e] * ewT[e * 64 + u];
      #pragma unroll 8
      for (int k = 0; k < Hd; ++k) acc += hcur[k] * gwT[k * 64 + u];

      float mu = acc;
      #pragma unroll
      for (int off = 1; off < 64; off <<= 1) mu += __shfl_xor(mu, off);
      mu *= (1.f / 64.f);
      float d = acc - mu;
      float var = d * d;
      #pragma unroll
      for (int off = 1; off < 64; off <<= 1) var += __shfl_xor(var, off);
      var *= (1.f / 64.f);
      float v = d * rsqrtf(var + LNEPS) * ln_g[round * Hd + u] + ln_b[round * Hd + u];
      hnew = fmaxf(v, 0.f);
    }
    __syncthreads();               // all reads of hcur done
    if (tid < 64) hcur[tid] = hnew;
    __syncthreads();
  }

  // ---- u/v precompute (threads 0..127; coalesced transposed W1 reads)
  if (tid < 64) {
    float acc = b1[tid];
    #pragma unroll 8
    for (int k = 0; k < Hd; ++k) acc += hcur[k] * W1aT[k * 64 + tid];
    uu[row * Hd + tid] = acc;
  } else if (tid < 128) {
    const int n = tid - 64;
    float acc = 0.f;
    #pragma unroll 8
    for (int k = 0; k < Hd; ++k) acc += hcur[k] * W1bT[k * 64 + n];
    vt[n * NSEQ + row] = acc;
  }
}

// --------------------------------------------------------------------------
// Edge MLP: thread per edge. z1[64] lives in VGPRs; W1c/W2/W3/b2 have
// wave-uniform indices -> scalar-pipe loads, fmac v,s,v at VALU issue peak.
__global__ __launch_bounds__(256) void k_mlp(
    const float* __restrict__ ef,
    const float* __restrict__ u, const float* __restrict__ vt,
    const float* __restrict__ W1,
    const float* __restrict__ W2, const float* __restrict__ b2,
    const float* __restrict__ W3, const float* __restrict__ b3,
    float* __restrict__ out)
{
  const int idx = blockIdx.x * 256 + threadIdx.x;   // < 320000
  const int b   = idx / (Nd * Nd);
  const int rem = idx - b * Nd * Nd;
  const int i   = rem / Nd;
  const int jj  = rem - i * Nd;

  const float* e = ef + (((b * Wd + (Wd - 1)) * Nd + i) * Nd + jj) * Ed;
  float e5[Ed];
  #pragma unroll
  for (int q = 0; q < Ed; ++q) e5[q] = e[q];

  const float* ur = u + (b * Nd + i) * Hd;
  const int vcol = b * Nd + jj;

  float z1[64];
  #pragma unroll
  for (int k = 0; k < 64; ++k) {
    float acc = ur[k] + vt[k * NSEQ + vcol];
    const float* w1c = W1 + k * 133 + 128;      // uniform -> scalar loads
    #pragma unroll
    for (int q = 0; q < Ed; ++q) acc += e5[q] * w1c[q];
    z1[k] = fmaxf(acc, 0.f);
  }

  float logit = b3[0];
  #pragma unroll 4
  for (int o = 0; o < 32; ++o) {
    float a0 = b2[o], a1 = 0.f, a2 = 0.f, a3 = 0.f;
    const float* w2 = W2 + o * 64;              // uniform -> scalar loads
    #pragma unroll
    for (int k = 0; k < 64; k += 4) {
      a0 += w2[k]     * z1[k];
      a1 += w2[k + 1] * z1[k + 1];
      a2 += w2[k + 2] * z1[k + 2];
      a3 += w2[k + 3] * z1[k + 3];
    }
    float z2 = fmaxf((a0 + a1) + (a2 + a3), 0.f);
    logit += W3[o] * z2;
  }
  out[idx] = 1.f / (1.f + __expf(-logit));
}

// --------------------------------------------------------------------------
extern "C" void kernel_launch(void* const* d_in, const int* in_sizes, int n_in,
                              void* d_out, int out_size, void* d_ws, size_t ws_size,
                              hipStream_t stream) {
  (void)in_sizes; (void)n_in; (void)out_size; (void)ws_size;
  const float* nf   = (const float*)d_in[0];
  const float* ef   = (const float*)d_in[1];
  const float* adj  = (const float*)d_in[2];
  const float* Wih0 = (const float*)d_in[3];
  const float* Whh0 = (const float*)d_in[4];
  const float* bih0 = (const float*)d_in[5];
  const float* bhh0 = (const float*)d_in[6];
  const float* Wih1 = (const float*)d_in[7];
  const float* Whh1 = (const float*)d_in[8];
  const float* bih1 = (const float*)d_in[9];
  const float* bhh1 = (const float*)d_in[10];
  const float* gcnW = (const float*)d_in[11];
  const float* gcnB = (const float*)d_in[12];
  const float* epW  = (const float*)d_in[13];
  const float* epB  = (const float*)d_in[14];
  const float* lnG  = (const float*)d_in[15];
  const float* lnB  = (const float*)d_in[16];
  const float* W1   = (const float*)d_in[17];
  const float* b1   = (const float*)d_in[18];
  const float* W2   = (const float*)d_in[19];
  const float* b2   = (const float*)d_in[20];
  const float* W3   = (const float*)d_in[21];
  const float* b3   = (const float*)d_in[22];
  float* out = (float*)d_out;

  // Workspace layout (floats). Total ~11.43M floats = 45.7 MB.
  float* ws    = (float*)d_ws;
  float* y0    = ws;                        // 1,228,800
  float* G1    = y0    + 1228800;           // 4,915,200
  float* G0    = G1    + 4915200;           // 4,915,200
  float* Wt1   = G0    + 4915200;           // 16,384
  float* h0    = Wt1   + 16384;             // 102,400
  float* uu    = h0    + 102400;            // 102,400
  float* vt    = uu    + 102400;            // 102,400
  float* gWT   = vt    + 102400;            // 8,192
  float* eWT   = gWT   + 8192;              // 640
  float* W1aT  = eWT   + 640;               // 4,096
  float* W1bT  = W1aT  + 4096;              // 4,096
  float* Wt0   = W1bT  + 4096;              // 1,536
  float* b0s   = Wt0   + 1536;              // 256
  float* WhhT0 = b0s   + 256;               // 16,384
  float* WhhT1 = WhhT0 + 16384;             // 16,384

  k_prep  <<<266,  256, 0, stream>>>(Wih1, gcnW, epW, W1, Wih0, bih0, bhh0,
                                     Whh0, Whh1, Wt1, gWT, eWT, W1aT, W1bT,
                                     Wt0, b0s, WhhT0, WhhT1);
  k_xproj0<<<2400, 256, 0, stream>>>(nf, Wt0, b0s, G0);
  k_lstm  <<<NSEQ/SEQB, 256, 0, stream>>>(G0, WhhT0, y0, h0, 1);
  k_xproj1<<<300,  256, 0, stream>>>(y0, Wt1, bih1, bhh1, G1);
  k_lstm  <<<NSEQ/SEQB, 256, 0, stream>>>(G1, WhhT1, y0, h0, 0);
  k_node  <<<1600, 256, 0, stream>>>(ef, adj, h0, gWT, gcnB, eWT, epB,
                                     lnG, lnB, W1aT, W1bT, b1, uu, vt);
  k_mlp   <<<1250, 256, 0, stream>>>(ef, uu, vt, W1, W2, b2, W3, b3, out);
}

// Round 10
// 304.740 us; speedup vs baseline: 1.2235x; 1.2235x over previous
//
#include <hip/hip_runtime.h>
#include <math.h>

// ---------------------------------------------------------------------------
// TemporalGCN: 2-layer LSTM (per-node sequences) -> 2 GCN rounds -> edge MLP.
//
// R9 post-mortem: k_lstm 79us at Occupancy 14.5% -- SEQB=4 shrank the grid
// to 400 blocks (grid starvation, same bug as R2), and in-loop G0/G1 reads
// streamed 19.6MB from HBM (FETCH 16.3MB, 656 GB/s). The LDS-weight idea
// was never tested at sane occupancy. R8's ~40us = L2-BW on per-step weight
// re-fetch (1.2 GB / 34.5 TB/s ~= 36us).
// R10 = LDS weights + 1600 blocks + no G stream:
//  * k_lstm0/1: SEQB=1, WhhT rows 0..57 in LDS [k][j] (conflict-free), 6
//    tail rows in regs. 2 blocks/CU. Zero global ops inside the t-loop.
//    R8's single-barrier + double-buffered gate_sh structure kept.
//  * k_xproj1 DELETED: lstm1 computes its own 12 G rows from y0 (3KB LDS)
//    via coalesced L2-hot Wt1 reads -> 12 registers. Removes G1 (19.6MB
//    write + read) and one launch. Bit-exact order kept (Sum_k then +bias).
//  * xproj0/G0 reverted to R8's in-kernel K=6 x-projection.
// All FP accumulation orders audited identical to R8 -> absmax 0.0.
// ---------------------------------------------------------------------------

#define Hd   64
#define Ed   5
#define Fd   6
#define Bd   8
#define Wd   12
#define Nd   200
#define NSEQ (Bd*Nd)        // 1600 sequences (b,n)
#define NG   (4*Hd)         // 256 gate rows
#define NEDGE (Bd*Nd*Nd)    // 320000 edges
#define WROWS 58            // Whh k-rows staged in LDS (58*256*4 = 59,392 B)
#define LNEPS 1e-5f

__device__ __forceinline__ float sigm(float x) { return 1.0f / (1.0f + __expf(-x)); }
__device__ __forceinline__ float tanh_fast(float x) {
  float ax = fabsf(x);
  float t  = __expf(-2.0f * ax);
  float r  = (1.0f - t) / (1.0f + t);
  return copysignf(r, x);
}

// --------------------------------------------------------------------------
// Prep (flat-index dispatch):
//  [0,16384)        Wt1[k][j]    = Wih1[j][k]
//  [16384,24576)    gcnWT[r][k][u]
//  [24576,25216)    epWT[r][e][u]
//  [25216,29312)    W1aT[k][n]
//  [29312,33408)    W1bT[k][n]
//  [33408,49792)    WhhT0[k][j]  = Whh0[j][k]
//  [49792,66176)    WhhT1[k][j]  = Whh1[j][k]
__global__ __launch_bounds__(256) void k_prep(
    const float* __restrict__ Wih1, const float* __restrict__ gcn_W,
    const float* __restrict__ ep_W, const float* __restrict__ W1,
    const float* __restrict__ Whh0, const float* __restrict__ Whh1,
    float* __restrict__ Wt1, float* __restrict__ gcnWT,
    float* __restrict__ epWT, float* __restrict__ W1aT,
    float* __restrict__ W1bT, float* __restrict__ WhhT0,
    float* __restrict__ WhhT1)
{
  int idx = blockIdx.x * 256 + threadIdx.x;
  if (idx < 16384) {
    int k = idx >> 8, j = idx & 255;
    Wt1[idx] = Wih1[j * Hd + k];
  } else if (idx < 24576) {
    int r0 = idx - 16384;
    int round = r0 >> 12, rem = r0 & 4095;
    int k = rem >> 6, u = rem & 63;
    gcnWT[r0] = gcn_W[round * 4096 + u * 64 + k];
  } else if (idx < 25216) {
    int r0 = idx - 24576;
    int round = r0 / 320, rem = r0 % 320;
    int e = rem >> 6, u = rem & 63;
    epWT[r0] = ep_W[round * 320 + u * Ed + e];
  } else if (idx < 29312) {
    int r0 = idx - 25216;
    int k = r0 >> 6, n = r0 & 63;
    W1aT[r0] = W1[n * 133 + k];
  } else if (idx < 33408) {
    int r0 = idx - 29312;
    int k = r0 >> 6, n = r0 & 63;
    W1bT[r0] = W1[n * 133 + 64 + k];
  } else if (idx < 49792) {
    int r0 = idx - 33408;
    int k = r0 >> 8, j = r0 & 255;
    WhhT0[r0] = Whh0[j * Hd + k];
  } else if (idx < 66176) {
    int r0 = idx - 49792;
    int k = r0 >> 8, j = r0 & 255;
    WhhT1[r0] = Whh1[j * Hd + k];
  }
}

// Weight access: rows 0..57 from LDS (lane-contiguous), 58..63 from regs.
#define WK(k) ((k) < WROWS ? w_lds[(k) * NG + j] : wtail[(k) - WROWS])

// --------------------------------------------------------------------------
// LSTM layer 0. 1600 blocks x 256 threads; block owns ONE sequence.
// Thread j = gate row j. WhhT in LDS; x-proj K=6 from regs (R8 order).
// Single barrier per step; no global memory ops inside the t-loop.
// LDS: 59,392 + 2048 + 256 + 288 = 61,984 B -> 2 blocks/CU.
__global__ __launch_bounds__(256) void k_lstm0(
    const float* __restrict__ nf,                       // (B,W,N,F)
    const float* __restrict__ Wih0, const float* __restrict__ bih0,
    const float* __restrict__ bhh0, const float* __restrict__ WhhT0,
    float* __restrict__ y0)                             // (NSEQ, W, H)
{
  __shared__ float w_lds[WROWS * NG];   // 59,392 B
  __shared__ float gate_sh[2][NG];      // 2,048 B (double-buffered)
  __shared__ float h_sh[Hd];            // 256 B
  __shared__ float x_sh[Wd * Fd];       // 288 B

  const int tid = threadIdx.x;
  const int seq = blockIdx.x;
  const int b = seq / Nd, n = seq % Nd;
  const int u = tid & 63;
  const int j = tid;

  for (int idx = tid; idx < WROWS * NG; idx += 256) w_lds[idx] = WhhT0[idx];
  float wtail[Hd - WROWS];
  #pragma unroll
  for (int q = 0; q < Hd - WROWS; ++q) wtail[q] = WhhT0[(WROWS + q) * NG + j];
  if (tid < Wd * Fd) {
    int t = tid / Fd, f = tid % Fd;
    x_sh[tid] = nf[((b * Wd + t) * Nd + n) * Fd + f];
  }
  h_sh[u] = 0.f;                        // 4x dup identical-value write

  float wx[Fd];
  #pragma unroll
  for (int f = 0; f < Fd; ++f) wx[f] = Wih0[j * Fd + f];
  const float bias = bih0[j] + bhh0[j];
  const int jt = j >> 6;                // 0=i,1=f,2=g,3=o (wave-uniform)

  float c = 0.f;                        // cell state for unit u (per-wave copy)
  float yreg[Wd];
  __syncthreads();

  #pragma unroll
  for (int t = 0; t < Wd; ++t) {
    const float* xp = x_sh + t * Fd;
    float a0 = bias, a1 = 0.f, a2 = 0.f, a3 = 0.f;
    #pragma unroll
    for (int f = 0; f < Fd; ++f) a1 += xp[f] * wx[f];
    const float4* h4 = (const float4*)h_sh;
    #pragma unroll
    for (int q = 0; q < 16; ++q) {
      float4 hv = h4[q];
      float w0 = WK(4 * q),     w1 = WK(4 * q + 1);
      float w2 = WK(4 * q + 2), w3 = WK(4 * q + 3);
      float d = hv.x * w0 + hv.y * w1 + hv.z * w2 + hv.w * w3;
      if ((q & 3) == 0) a0 += d; else if ((q & 3) == 1) a1 += d;
      else if ((q & 3) == 2) a2 += d; else a3 += d;
    }
    float acc = (a0 + a1) + (a2 + a3);
    gate_sh[t & 1][j] = (jt == 2) ? tanh_fast(acc) : sigm(acc);
    __syncthreads();                    // the ONLY barrier per step
    const float* gb = gate_sh[t & 1];
    float iv = gb[u];
    float fv = gb[64 + u];
    float gv = gb[128 + u];
    float ov = gb[192 + u];
    c = fv * c + iv * gv;
    float h = ov * tanh_fast(c);
    h_sh[u] = h;                        // dup identical-value writes: benign
    yreg[t] = h;
  }
  if (tid < Hd) {
    #pragma unroll
    for (int t = 0; t < Wd; ++t)
      y0[seq * (Wd * Hd) + t * Hd + u] = yreg[t];   // coalesced 256B stores
  }
}

// --------------------------------------------------------------------------
// LSTM layer 1 WITH FUSED input projection. 1600 blocks x 256 threads.
// Stages y0[seq] (768 floats) into LDS, computes its own 12 G rows into
// registers (g[12], coalesced L2-hot Wt1 reads, Sum_k-then-bias order ==
// old k_xproj1), then runs the same single-barrier recurrence.
// LDS: 59,392 + 2048 + 256 + 3072 = 64,768 B -> 2 blocks/CU.
__global__ __launch_bounds__(256) void k_lstm1(
    const float* __restrict__ y0,     // (NSEQ, Wd, Hd)
    const float* __restrict__ Wt1,    // (64, 256) transposed Wih1
    const float* __restrict__ bih1, const float* __restrict__ bhh1,
    const float* __restrict__ WhhT1,
    float* __restrict__ hout)         // (NSEQ, Hd)
{
  __shared__ float w_lds[WROWS * NG];   // 59,392 B
  __shared__ float gate_sh[2][NG];      // 2,048 B
  __shared__ float h_sh[Hd];            // 256 B
  __shared__ float y0sh[Wd * Hd];       // 3,072 B

  const int tid = threadIdx.x;
  const int seq = blockIdx.x;
  const int u = tid & 63;
  const int j = tid;

  for (int idx = tid; idx < WROWS * NG; idx += 256) w_lds[idx] = WhhT1[idx];
  float wtail[Hd - WROWS];
  #pragma unroll
  for (int q = 0; q < Hd - WROWS; ++q) wtail[q] = WhhT1[(WROWS + q) * NG + j];
  for (int idx = tid; idx < Wd * Hd; idx += 256)
    y0sh[idx] = y0[seq * (Wd * Hd) + idx];
  h_sh[u] = 0.f;
  __syncthreads();

  // Fused x-projection: g[t] = Sum_k y0[t][k]*Wt1[k][j]  (+ bias after).
  // Same fmaf / k-ascending / bias-last order as the old k_xproj1.
  float g[Wd];
  #pragma unroll
  for (int t = 0; t < Wd; ++t) g[t] = 0.f;
  for (int k = 0; k < Hd; ++k) {
    float wv = Wt1[k * NG + j];         // coalesced, L2-hot (64KB shared)
    #pragma unroll
    for (int t = 0; t < Wd; ++t)
      g[t] = fmaf(y0sh[t * Hd + k], wv, g[t]);   // broadcast LDS read
  }
  const float bsum = bih1[j] + bhh1[j];
  #pragma unroll
  for (int t = 0; t < Wd; ++t) g[t] += bsum;

  const int jt = j >> 6;
  float c = 0.f;
  float hlast = 0.f;

  #pragma unroll
  for (int t = 0; t < Wd; ++t) {
    float a0 = g[t];                    // bias+proj, register-resident
    float a1 = 0.f, a2 = 0.f, a3 = 0.f;
    const float4* h4 = (const float4*)h_sh;
    #pragma unroll
    for (int q = 0; q < 16; ++q) {
      float4 hv = h4[q];
      float w0 = WK(4 * q),     w1 = WK(4 * q + 1);
      float w2 = WK(4 * q + 2), w3 = WK(4 * q + 3);
      float d = hv.x * w0 + hv.y * w1 + hv.z * w2 + hv.w * w3;
      if ((q & 3) == 0) a0 += d; else if ((q & 3) == 1) a1 += d;
      else if ((q & 3) == 2) a2 += d; else a3 += d;
    }
    float acc = (a0 + a1) + (a2 + a3);
    gate_sh[t & 1][j] = (jt == 2) ? tanh_fast(acc) : sigm(acc);
    __syncthreads();                    // the ONLY barrier per step
    const float* gb = gate_sh[t & 1];
    float iv = gb[u];
    float fv = gb[64 + u];
    float gv = gb[128 + u];
    float ov = gb[192 + u];
    c = fv * c + iv * gv;
    float h = ov * tanh_fast(c);
    h_sh[u] = h;
    hlast = h;
  }
  if (tid < Hd) hout[seq * Hd + u] = hlast;
}

// --------------------------------------------------------------------------
// Fused per-row node pipeline: wsum -> GCN r0 -> GCN r1 -> u/v precompute.
// One block per row (b,i); 256 threads. adj/ef rows staged into LDS with
// COALESCED loads; all weight reads coalesced via the k_prep transposes.
__global__ __launch_bounds__(256) void k_node(
    const float* __restrict__ ef,    const float* __restrict__ adj,
    const float* __restrict__ h0,
    const float* __restrict__ gcnWT, const float* __restrict__ gcn_b,
    const float* __restrict__ epWT,  const float* __restrict__ ep_b,
    const float* __restrict__ ln_g,  const float* __restrict__ ln_b,
    const float* __restrict__ W1aT,  const float* __restrict__ W1bT,
    const float* __restrict__ b1,
    float* __restrict__ uu, float* __restrict__ vt)
{
  __shared__ float ef_sh[Nd * Ed];   // 1000: edge_last row (coalesced stage)
  __shared__ float adj_sh[Nd];       // 200
  __shared__ float red[4][6];
  __shared__ float w6[6];
  __shared__ float hcur[Hd];

  const int row = blockIdx.x;      // b*200+i
  const int b = row / Nd, i = row % Nd;
  const int tid = threadIdx.x;

  const float* efrow = ef + (size_t)(((b * Wd + (Wd - 1)) * Nd + i)) * (Nd * Ed);
  for (int idx = tid; idx < Nd * Ed; idx += 256) ef_sh[idx] = efrow[idx];
  const float* adjrow = adj + (b * Nd + i) * Nd;
  if (tid < Nd) adj_sh[tid] = adjrow[tid];
  if (tid < Hd) hcur[tid] = h0[row * Hd + tid];
  __syncthreads();

  // ---- wsum: p[e] = sum_j adj*edge[e], p[5] = sum_j adj (order as before)
  float p[6] = {0.f, 0.f, 0.f, 0.f, 0.f, 0.f};
  if (tid < Nd) {
    float a = adj_sh[tid];
    p[5] = a;
    #pragma unroll
    for (int k = 0; k < Ed; ++k) p[k] = a * ef_sh[tid * Ed + k];
  }
  #pragma unroll
  for (int k = 0; k < 6; ++k) {
    float v = p[k];
    for (int off = 32; off > 0; off >>= 1) v += __shfl_down(v, off);
    p[k] = v;
  }
  if ((tid & 63) == 0) {
    #pragma unroll
    for (int k = 0; k < 6; ++k) red[tid >> 6][k] = p[k];
  }
  __syncthreads();
  if (tid < 6)
    w6[tid] = red[0][tid] + red[1][tid] + red[2][tid] + red[3][tid];
  __syncthreads();

  // ---- 2 GCN rounds (wave 0; coalesced transposed-weight reads)
  const int u = tid & 63;
  #pragma unroll
  for (int round = 0; round < 2; ++round) {
    float hnew = 0.f;
    if (tid < 64) {
      const float* gwT = gcnWT + round * 4096;   // [k][u]
      const float* ewT = epWT  + round * 320;    // [e][u]
      float acc = gcn_b[round * Hd + u] + w6[5] * ep_b[round * Hd + u];
      #pragma unroll
      for (int e = 0; e < Ed; ++e) acc += w6[e] * ewT[e * 64 + u];
      #pragma unroll 8
      for (int k = 0; k < Hd; ++k) acc += hcur[k] * gwT[k * 64 + u];

      float mu = acc;
      #pragma unroll
      for (int off = 1; off < 64; off <<= 1) mu += __shfl_xor(mu, off);
      mu *= (1.f / 64.f);
      float d = acc - mu;
      float var = d * d;
      #pragma unroll
      for (int off = 1; off < 64; off <<= 1) var += __shfl_xor(var, off);
      var *= (1.f / 64.f);
      float v = d * rsqrtf(var + LNEPS) * ln_g[round * Hd + u] + ln_b[round * Hd + u];
      hnew = fmaxf(v, 0.f);
    }
    __syncthreads();               // all reads of hcur done
    if (tid < 64) hcur[tid] = hnew;
    __syncthreads();
  }

  // ---- u/v precompute (threads 0..127; coalesced transposed W1 reads)
  if (tid < 64) {
    float acc = b1[tid];
    #pragma unroll 8
    for (int k = 0; k < Hd; ++k) acc += hcur[k] * W1aT[k * 64 + tid];
    uu[row * Hd + tid] = acc;
  } else if (tid < 128) {
    const int n = tid - 64;
    float acc = 0.f;
    #pragma unroll 8
    for (int k = 0; k < Hd; ++k) acc += hcur[k] * W1bT[k * 64 + n];
    vt[n * NSEQ + row] = acc;
  }
}

// --------------------------------------------------------------------------
// Edge MLP: thread per edge. z1[64] lives in VGPRs; W1c/W2/W3/b2 have
// wave-uniform indices -> scalar-pipe loads, fmac v,s,v at VALU issue peak.
__global__ __launch_bounds__(256) void k_mlp(
    const float* __restrict__ ef,
    const float* __restrict__ u, const float* __restrict__ vt,
    const float* __restrict__ W1,
    const float* __restrict__ W2, const float* __restrict__ b2,
    const float* __restrict__ W3, const float* __restrict__ b3,
    float* __restrict__ out)
{
  const int idx = blockIdx.x * 256 + threadIdx.x;   // < 320000
  const int b   = idx / (Nd * Nd);
  const int rem = idx - b * Nd * Nd;
  const int i   = rem / Nd;
  const int jj  = rem - i * Nd;

  const float* e = ef + (((b * Wd + (Wd - 1)) * Nd + i) * Nd + jj) * Ed;
  float e5[Ed];
  #pragma unroll
  for (int q = 0; q < Ed; ++q) e5[q] = e[q];

  const float* ur = u + (b * Nd + i) * Hd;
  const int vcol = b * Nd + jj;

  float z1[64];
  #pragma unroll
  for (int k = 0; k < 64; ++k) {
    float acc = ur[k] + vt[k * NSEQ + vcol];
    const float* w1c = W1 + k * 133 + 128;      // uniform -> scalar loads
    #pragma unroll
    for (int q = 0; q < Ed; ++q) acc += e5[q] * w1c[q];
    z1[k] = fmaxf(acc, 0.f);
  }

  float logit = b3[0];
  #pragma unroll 4
  for (int o = 0; o < 32; ++o) {
    float a0 = b2[o], a1 = 0.f, a2 = 0.f, a3 = 0.f;
    const float* w2 = W2 + o * 64;              // uniform -> scalar loads
    #pragma unroll
    for (int k = 0; k < 64; k += 4) {
      a0 += w2[k]     * z1[k];
      a1 += w2[k + 1] * z1[k + 1];
      a2 += w2[k + 2] * z1[k + 2];
      a3 += w2[k + 3] * z1[k + 3];
    }
    float z2 = fmaxf((a0 + a1) + (a2 + a3), 0.f);
    logit += W3[o] * z2;
  }
  out[idx] = 1.f / (1.f + __expf(-logit));
}

// --------------------------------------------------------------------------
extern "C" void kernel_launch(void* const* d_in, const int* in_sizes, int n_in,
                              void* d_out, int out_size, void* d_ws, size_t ws_size,
                              hipStream_t stream) {
  (void)in_sizes; (void)n_in; (void)out_size; (void)ws_size;
  const float* nf   = (const float*)d_in[0];
  const float* ef   = (const float*)d_in[1];
  const float* adj  = (const float*)d_in[2];
  const float* Wih0 = (const float*)d_in[3];
  const float* Whh0 = (const float*)d_in[4];
  const float* bih0 = (const float*)d_in[5];
  const float* bhh0 = (const float*)d_in[6];
  const float* Wih1 = (const float*)d_in[7];
  const float* Whh1 = (const float*)d_in[8];
  const float* bih1 = (const float*)d_in[9];
  const float* bhh1 = (const float*)d_in[10];
  const float* gcnW = (const float*)d_in[11];
  const float* gcnB = (const float*)d_in[12];
  const float* epW  = (const float*)d_in[13];
  const float* epB  = (const float*)d_in[14];
  const float* lnG  = (const float*)d_in[15];
  const float* lnB  = (const float*)d_in[16];
  const float* W1   = (const float*)d_in[17];
  const float* b1   = (const float*)d_in[18];
  const float* W2   = (const float*)d_in[19];
  const float* b2   = (const float*)d_in[20];
  const float* W3   = (const float*)d_in[21];
  const float* b3   = (const float*)d_in[22];
  float* out = (float*)d_out;

  // Workspace layout (floats). Total ~1.6M floats = 6.4 MB.
  float* ws    = (float*)d_ws;
  float* y0    = ws;                        // 1,228,800
  float* Wt1   = y0    + 1228800;           // 16,384
  float* h0    = Wt1   + 16384;             // 102,400
  float* uu    = h0    + 102400;            // 102,400
  float* vt    = uu    + 102400;            // 102,400
  float* gWT   = vt    + 102400;            // 8,192
  float* eWT   = gWT   + 8192;              // 640
  float* W1aT  = eWT   + 640;               // 4,096
  float* W1bT  = W1aT  + 4096;              // 4,096
  float* WhhT0 = W1bT  + 4096;              // 16,384
  float* WhhT1 = WhhT0 + 16384;             // 16,384

  k_prep  <<<259,  256, 0, stream>>>(Wih1, gcnW, epW, W1, Whh0, Whh1,
                                     Wt1, gWT, eWT, W1aT, W1bT, WhhT0, WhhT1);
  k_lstm0 <<<NSEQ, 256, 0, stream>>>(nf, Wih0, bih0, bhh0, WhhT0, y0);
  k_lstm1 <<<NSEQ, 256, 0, stream>>>(y0, Wt1, bih1, bhh1, WhhT1, h0);
  k_node  <<<1600, 256, 0, stream>>>(ef, adj, h0, gWT, gcnB, eWT, epB,
                                     lnG, lnB, W1aT, W1bT, b1, uu, vt);
  k_mlp   <<<1250, 256, 0, stream>>>(ef, uu, vt, W1, W2, b2, W3, b3, out);
}